// Round 1
// baseline (952.311 us; speedup 1.0000x reference)
//
#include <hip/hip_runtime.h>

// AdLIF SNN forward, MI355X.
// B=512, T=500, NIN=96, H=512, NOUT=2.
// Strategy: one block per batch row (recurrence couples only within a row).
// Thread h owns neuron h: W1 row in 96 VGPRs, state (v, spk, a) in registers.
// Recurrent spk@Wrec^T is gated by __syncthreads_count (expected always 0
// spikes with these scales) -> cold path, exact when taken.

#define B_ 512
#define T_ 500
#define NIN_ 96
#define H_ 512

__global__ __launch_bounds__(512, 2) void snn_fused(
    const float* __restrict__ x,      // [B, T, NIN]
    const float* __restrict__ W1,     // [H, NIN]
    const float* __restrict__ Wrec,   // [H, H]
    const float* __restrict__ W2,     // [2, H]
    const float* __restrict__ alpha,  // [H]
    const float* __restrict__ rho,    // [H]
    const float* __restrict__ beta_a, // [H]
    float* __restrict__ out)          // [B, 2]
{
    const int b = blockIdx.x;
    const int h = threadIdx.x;

    __shared__ float4 xlds[2][24];   // double-buffered x_t (96 floats)
    __shared__ float  spk_lds[H_];   // previous-step spikes (for cold path)
    __shared__ float  red[16];       // readout reduction

    // W1 row h -> 96 VGPRs (reused 500x)
    float4 w4[24];
    {
        const float4* w1row = reinterpret_cast<const float4*>(W1 + (size_t)h * NIN_);
        #pragma unroll
        for (int i = 0; i < 24; ++i) w4[i] = w1row[i];
    }

    const float al       = alpha[h];
    const float one_m_al = 1.0f - al;
    const float rh       = rho[h];
    const float be       = beta_a[h];

    float v = 0.0f, a = 0.0f, spk = 0.0f;
    spk_lds[h] = 0.0f;

    const float4* xrow = reinterpret_cast<const float4*>(x + (size_t)b * (T_ * NIN_));
    if (h < 24) xlds[0][h] = xrow[h];   // stage t=0

    for (int t = 0; t < T_; ++t) {
        // Barrier: everyone finished step t-1 (xlds reads + spk_lds writes
        // visible). Also counts previous-step spikes across the block.
        int cnt = __syncthreads_count(spk != 0.0f);

        // Prefetch x_{t+1} into registers (latency hidden under compute).
        float4 xn = make_float4(0.f, 0.f, 0.f, 0.f);
        if (h < 24 && (t + 1) < T_) xn = xrow[(size_t)(t + 1) * 24 + h];

        // I_h = dot(x_t, W1[h,:]) -- 24x ds_read_b128 broadcast + 96 FMA,
        // 4 independent accumulators to break the fmac dependency chain.
        const float4* xc = xlds[t & 1];
        float I0 = 0.f, I1 = 0.f, I2 = 0.f, I3 = 0.f;
        #pragma unroll
        for (int i = 0; i < 24; ++i) {
            float4 xv = xc[i];
            I0 = fmaf(xv.x, w4[i].x, I0);
            I1 = fmaf(xv.y, w4[i].y, I1);
            I2 = fmaf(xv.z, w4[i].z, I2);
            I3 = fmaf(xv.w, w4[i].w, I3);
        }
        float I = (I0 + I1) + (I2 + I3);

        // Recurrent input: only if any neuron in this row spiked last step.
        if (cnt > 0) {
            const float* wr = Wrec + (size_t)h * H_;  // I_h += sum Wrec[h, h']
            for (int hp = 0; hp < H_; ++hp) {
                if (spk_lds[hp] != 0.0f) I += wr[hp];
            }
            __syncthreads();  // readers done before spk_lds is rewritten
        }

        // AdLIF update (matches reference op order).
        float vnew = fmaf(al * v, (1.0f - spk), one_m_al * (I - a));
        spk = (vnew - 1.0f) > 0.0f ? 1.0f : 0.0f;
        a = fmaf(be, spk, rh * a);
        v = vnew;

        // Publish next x tile + this step's spikes (visible after next barrier).
        if (h < 24 && (t + 1) < T_) xlds[(t + 1) & 1][h] = xn;
        spk_lds[h] = spk;
    }

    // Readout: out[b,n] = sum_h v_h * W2[n,h]
    float p0 = v * W2[h];
    float p1 = v * W2[H_ + h];
    #pragma unroll
    for (int off = 32; off > 0; off >>= 1) {
        p0 += __shfl_down(p0, off, 64);
        p1 += __shfl_down(p1, off, 64);
    }
    const int wave = h >> 6, lane = h & 63;
    if (lane == 0) { red[wave * 2] = p0; red[wave * 2 + 1] = p1; }
    __syncthreads();
    if (h == 0) {
        float s0 = 0.f, s1 = 0.f;
        #pragma unroll
        for (int wv = 0; wv < 8; ++wv) { s0 += red[wv * 2]; s1 += red[wv * 2 + 1]; }
        out[b * 2 + 0] = s0;
        out[b * 2 + 1] = s1;
    }
}

extern "C" void kernel_launch(void* const* d_in, const int* in_sizes, int n_in,
                              void* d_out, int out_size, void* d_ws, size_t ws_size,
                              hipStream_t stream) {
    const float* x      = (const float*)d_in[0];
    const float* W1     = (const float*)d_in[1];
    const float* Wrec   = (const float*)d_in[2];
    const float* W2     = (const float*)d_in[3];
    const float* alpha  = (const float*)d_in[4];
    const float* rho    = (const float*)d_in[5];
    const float* beta_a = (const float*)d_in[6];
    float* out = (float*)d_out;

    snn_fused<<<dim3(B_), dim3(H_), 0, stream>>>(x, W1, Wrec, W2, alpha, rho, beta_a, out);
}

// Round 2
// 71.476 us; speedup vs baseline: 13.3235x; 13.3235x over previous
//
#include <hip/hip_runtime.h>
#include <hip/hip_bf16.h>

// AdLIF SNN forward, MI355X. B=512, T=500, NIN=96, H=512, NOUT=2.
//
// Per block: one batch row, 512 threads (8 waves).
// - Input projection via MFMA 16x16x32 bf16, 16 timesteps per chunk:
//   each wave holds 4 W1 h-tile fragments (A operand) in registers for the
//   whole kernel; x-chunk staged in LDS (bf16, double buffered) is the B
//   operand; D[h][t] -> I_lds[t][h] (f32).
// - Scan runs 16 steps barrier-free per thread (own-spike reset is register
//   local). Cross-neuron recurrence (spk @ Wrec^T) is speculated away:
//   checkpoint at chunk start, LDS flag detects any spike in chunk, on
//   detection the chunk is rerun exactly and the kernel goes sticky-exact.
//   Correct for any input: the first true spike is always reproduced by the
//   speculative run (dynamics identical until it occurs).
// - 2 barriers per chunk (64 total) vs 500+ before.

#define B_ 512
#define T_ 500
#define NIN_ 96
#define H_ 512
#define CH 16
#define NCH 32            // 31 full chunks + 1 partial (4 steps)
#define XPAD 104          // bf16 per x_lds row (16B-aligned rows, 2-way banks)
#define IPAD 516          // f32 per I_lds row (16B-aligned, conflict-checked)

typedef __attribute__((ext_vector_type(8))) short bf16x8;  // 8 bf16 = 4 VGPR
typedef __attribute__((ext_vector_type(4))) float f32x4;

__device__ __forceinline__ unsigned short f2bf(float f) {
    union { __hip_bfloat16 h; unsigned short s; } u;
    u.h = __float2bfloat16(f);
    return u.s;
}

// Exact AdLIF steps with recurrent input from spk_lds (cold path).
__device__ __forceinline__ void exact_steps(
    int nsteps, const float* Ilds, float* spk_lds, const float* __restrict__ Wrec,
    int tid, float al, float oma, float rh, float be,
    float& v, float& a, float& spk)
{
    for (int tt = 0; tt < nsteps; ++tt) {
        float I = Ilds[tt * IPAD + tid];
        float racc = 0.f;
        for (int hp = 0; hp < H_; ++hp) {
            float s = spk_lds[hp];
            if (s != 0.f) racc += Wrec[(size_t)tid * H_ + hp];  // spikes are 1.0
        }
        float vnew = (al * v) * (1.f - spk) + oma * ((I + racc) - a);
        spk = (vnew - 1.f) > 0.f ? 1.f : 0.f;
        a = fmaf(be, spk, rh * a);
        v = vnew;
        __syncthreads();
        spk_lds[tid] = spk;
        __syncthreads();
    }
}

__device__ __forceinline__ void stage_chunk(
    const float4* __restrict__ xb4, unsigned short* dst, int c, int st, int sq, int active)
{
    if (!active) return;
    int t = c * CH + st;
    float4 xv = make_float4(0.f, 0.f, 0.f, 0.f);
    if (t < T_) xv = xb4[t * 24 + sq];
    uint2 w;
    w.x = (unsigned int)f2bf(xv.x) | ((unsigned int)f2bf(xv.y) << 16);
    w.y = (unsigned int)f2bf(xv.z) | ((unsigned int)f2bf(xv.w) << 16);
    *reinterpret_cast<uint2*>(dst + st * XPAD + sq * 4) = w;
}

__global__ __launch_bounds__(512, 4) void snn_mfma(
    const float* __restrict__ x,      // [B, T, NIN]
    const float* __restrict__ W1,     // [H, NIN]
    const float* __restrict__ Wrec,   // [H, H]
    const float* __restrict__ W2,     // [2, H]
    const float* __restrict__ alpha,  // [H]
    const float* __restrict__ rho,    // [H]
    const float* __restrict__ beta_a, // [H]
    float* __restrict__ out)          // [B, 2]
{
    const int b    = blockIdx.x;
    const int tid  = threadIdx.x;
    const int wv   = tid >> 6;
    const int lane = tid & 63;
    const int lq   = lane >> 4;      // k-quad (0..3)
    const int lr   = lane & 15;      // row within 16

    __shared__ unsigned short xlds[2][CH * XPAD]; // x chunk, bf16
    __shared__ float Ilds[CH * IPAD];             // I[t][h], f32
    __shared__ float spk_lds[H_];
    __shared__ int   flagLds[2];
    __shared__ float red[16];

    // --- W1 fragments: wave wv owns h-tiles wv*64 + i*16, i=0..3.
    // Fragment layout (16x16x32): lane holds row (l&15), k = 8*(l>>4)+j.
    bf16x8 afrag[4][3];
    #pragma unroll
    for (int i = 0; i < 4; ++i) {
        const int h = wv * 64 + i * 16 + lr;
        const float* wrow = W1 + h * NIN_;
        #pragma unroll
        for (int kb = 0; kb < 3; ++kb) {
            const float* p = wrow + kb * 32 + lq * 8;
            float4 u0 = *reinterpret_cast<const float4*>(p);
            float4 u1 = *reinterpret_cast<const float4*>(p + 4);
            union { unsigned short s[8]; bf16x8 v; } pk;
            pk.s[0] = f2bf(u0.x); pk.s[1] = f2bf(u0.y);
            pk.s[2] = f2bf(u0.z); pk.s[3] = f2bf(u0.w);
            pk.s[4] = f2bf(u1.x); pk.s[5] = f2bf(u1.y);
            pk.s[6] = f2bf(u1.z); pk.s[7] = f2bf(u1.w);
            afrag[i][kb] = pk.v;
        }
    }

    const float al  = alpha[tid];
    const float oma = 1.0f - al;
    const float rh  = rho[tid];
    const float be  = beta_a[tid];

    const float4* xb4 = reinterpret_cast<const float4*>(x + (size_t)b * T_ * NIN_);
    const int st = tid / 24, sq = tid % 24;
    const int stager = (tid < 384);

    stage_chunk(xb4, xlds[0], 0, st, sq, stager);   // chunk 0
    if (tid == 0) { flagLds[0] = 0; flagLds[1] = 0; }

    float v = 0.f, a = 0.f, spk = 0.f;
    float v0 = 0.f, a0 = 0.f, spk0 = 0.f;
    int exactMode = 0;

    for (int c = 0; c < NCH; ++c) {
        __syncthreads();   // S(c): x_lds[c&1] + flags(c-1) visible

        // Validate chunk c-1 speculation (I_lds still holds chunk c-1).
        if (c > 0 && !exactMode) {
            int f = flagLds[(c - 1) & 1];
            if (f) {            // uniform branch
                v = v0; a = a0; spk = spk0;
                spk_lds[tid] = spk;
                __syncthreads();
                exact_steps(CH, Ilds, spk_lds, Wrec, tid, al, oma, rh, be, v, a, spk);
                exactMode = 1;
            }
        }
        // checkpoint (start of chunk c)
        v0 = v; a0 = a; spk0 = spk;

        // --- MFMA: I[t][h] for chunk c from xlds[c&1]
        f32x4 acc[4] = {{0.f,0.f,0.f,0.f},{0.f,0.f,0.f,0.f},
                        {0.f,0.f,0.f,0.f},{0.f,0.f,0.f,0.f}};
        #pragma unroll
        for (int kb = 0; kb < 3; ++kb) {
            bf16x8 xf = *reinterpret_cast<const bf16x8*>(
                &xlds[c & 1][lr * XPAD + kb * 32 + lq * 8]);
            #pragma unroll
            for (int i = 0; i < 4; ++i)
                acc[i] = __builtin_amdgcn_mfma_f32_16x16x32_bf16(
                    afrag[i][kb], xf, acc[i], 0, 0, 0);
        }
        // D: col(t)=lane&15, row(h_local)=4*(lane>>4)+reg -> contiguous h: b128
        #pragma unroll
        for (int i = 0; i < 4; ++i)
            *reinterpret_cast<f32x4*>(
                &Ilds[lr * IPAD + wv * 64 + i * 16 + lq * 4]) = acc[i];

        if (c + 1 < NCH) stage_chunk(xb4, xlds[(c + 1) & 1], c + 1, st, sq, stager);
        if (tid == 0) flagLds[c & 1] = 0;   // slot for THIS chunk's detection

        __syncthreads();   // E(c): I_lds + x_lds[next] ready

        const int steps = (c == NCH - 1) ? (T_ - (NCH - 1) * CH) : CH;

        if (!exactMode) {
            int anyspk = 0;
            if (steps == CH) {
                #pragma unroll
                for (int tt = 0; tt < CH; ++tt) {
                    float I = Ilds[tt * IPAD + tid];
                    float vnew = fmaf(al * v, 1.f - spk, oma * (I - a));
                    spk = (vnew - 1.f) > 0.f ? 1.f : 0.f;
                    anyspk |= (int)(vnew > 1.f);
                    a = fmaf(be, spk, rh * a);
                    v = vnew;
                }
            } else {
                for (int tt = 0; tt < steps; ++tt) {
                    float I = Ilds[tt * IPAD + tid];
                    float vnew = fmaf(al * v, 1.f - spk, oma * (I - a));
                    spk = (vnew - 1.f) > 0.f ? 1.f : 0.f;
                    anyspk |= (int)(vnew > 1.f);
                    a = fmaf(be, spk, rh * a);
                    v = vnew;
                }
            }
            if (anyspk) flagLds[c & 1] = 1;  // benign race: all writers store 1
        } else {
            exact_steps(steps, Ilds, spk_lds, Wrec, tid, al, oma, rh, be, v, a, spk);
        }
    }

    // Epilogue: validate the last chunk's speculation.
    __syncthreads();
    if (!exactMode && flagLds[(NCH - 1) & 1]) {
        v = v0; a = a0; spk = spk0;
        spk_lds[tid] = spk;
        __syncthreads();
        exact_steps(T_ - (NCH - 1) * CH, Ilds, spk_lds, Wrec,
                    tid, al, oma, rh, be, v, a, spk);
    }

    // Readout: out[b,n] = sum_h v_h * W2[n,h]
    float p0 = v * W2[tid];
    float p1 = v * W2[H_ + tid];
    #pragma unroll
    for (int off = 32; off > 0; off >>= 1) {
        p0 += __shfl_down(p0, off, 64);
        p1 += __shfl_down(p1, off, 64);
    }
    if (lane == 0) { red[wv * 2] = p0; red[wv * 2 + 1] = p1; }
    __syncthreads();
    if (tid == 0) {
        float s0 = 0.f, s1 = 0.f;
        #pragma unroll
        for (int w8 = 0; w8 < 8; ++w8) { s0 += red[w8 * 2]; s1 += red[w8 * 2 + 1]; }
        out[b * 2 + 0] = s0;
        out[b * 2 + 1] = s1;
    }
}

extern "C" void kernel_launch(void* const* d_in, const int* in_sizes, int n_in,
                              void* d_out, int out_size, void* d_ws, size_t ws_size,
                              hipStream_t stream) {
    const float* x      = (const float*)d_in[0];
    const float* W1     = (const float*)d_in[1];
    const float* Wrec   = (const float*)d_in[2];
    const float* W2     = (const float*)d_in[3];
    const float* alpha  = (const float*)d_in[4];
    const float* rho    = (const float*)d_in[5];
    const float* beta_a = (const float*)d_in[6];
    float* out = (float*)d_out;

    snn_mfma<<<dim3(B_), dim3(H_), 0, stream>>>(x, W1, Wrec, W2, alpha, rho, beta_a, out);
}